// Round 1
// baseline (1956.090 us; speedup 1.0000x reference)
//
#include <hip/hip_runtime.h>
#include <hip/hip_bf16.h>

#define TS 16

// C[m,n] = sum_k A[m,k] * W[n,k] + bias[n]   (A: MxK row-major, W: NxK row-major)
__global__ void gemm_nt(const float* __restrict__ A, const float* __restrict__ W,
                        const float* __restrict__ bias, float* __restrict__ C,
                        int M, int Nn, int Kk) {
    __shared__ float As[TS][TS + 1];
    __shared__ float Ws[TS][TS + 1];
    int tx = threadIdx.x, ty = threadIdx.y;
    int row = blockIdx.y * TS + ty;      // m
    int col = blockIdx.x * TS + tx;      // n
    int wrow = blockIdx.x * TS + ty;     // n-row staged by this thread
    float acc = 0.f;
    for (int k0 = 0; k0 < Kk; k0 += TS) {
        As[ty][tx] = A[row * Kk + k0 + tx];
        Ws[ty][tx] = W[wrow * Kk + k0 + tx];
        __syncthreads();
#pragma unroll
        for (int kk = 0; kk < TS; ++kk) acc += As[ty][kk] * Ws[tx][kk];
        __syncthreads();
    }
    C[row * Nn + col] = acc + bias[col];
}

// One block per query point. 256 threads = 8 heads x 32 dims.
// qkv row layout: [q(256) | k(256) | v(256)], x: (N,256)
__global__ void attn_kernel(const float* __restrict__ qkv, const int* __restrict__ index_1,
                            float* __restrict__ x) {
    const int i = blockIdx.x;
    const int t = threadIdx.x;
    const int h = t >> 5;    // head 0..7
    const int d = t & 31;    // dim within head

    __shared__ int nbr[16];
    __shared__ float w[8][16];

    if (t < 16) nbr[t] = index_1[i * 16 + t];
    __syncthreads();

    const float scale = 0.1767766952966369f;  // 1/sqrt(32)
    const float qv = qkv[i * 768 + h * 32 + d] * scale;

#pragma unroll
    for (int m = 0; m < 16; ++m) {
        const int j = nbr[m];
        float p = qv * qkv[j * 768 + 256 + h * 32 + d];
        // butterfly reduce over the 32 lanes of this head
#pragma unroll
        for (int off = 16; off > 0; off >>= 1) p += __shfl_xor(p, off, 32);
        if (d == 0) w[h][m] = p;
    }
    __syncthreads();

    if (d == 0) {
        float mx = -1e30f;
#pragma unroll
        for (int m = 0; m < 16; ++m) mx = fmaxf(mx, w[h][m]);
        float s = 0.f;
#pragma unroll
        for (int m = 0; m < 16; ++m) { float e = expf(w[h][m] - mx); w[h][m] = e; s += e; }
        const float inv = 1.f / s;
#pragma unroll
        for (int m = 0; m < 16; ++m) w[h][m] *= inv;
    }
    __syncthreads();

    float acc = 0.f;
#pragma unroll
    for (int m = 0; m < 16; ++m) {
        const int j = nbr[m];
        acc += w[h][m] * qkv[j * 768 + 512 + h * 32 + d];
    }
    x[i * 256 + t] = acc;
}

extern "C" void kernel_launch(void* const* d_in, const int* in_sizes, int n_in,
                              void* d_out, int out_size, void* d_ws, size_t ws_size,
                              hipStream_t stream) {
    const float* feats   = (const float*)d_in[0];
    // d_in[1] = xyz (unused), d_in[2] = index_0 (implicit), d_in[4] = offsets (uniform), d_in[5] = n_max
    const int*   index_1 = (const int*)d_in[3];
    const float* qkv_w   = (const float*)d_in[6];
    const float* qkv_b   = (const float*)d_in[7];
    const float* proj_w  = (const float*)d_in[8];
    const float* proj_b  = (const float*)d_in[9];
    float* out = (float*)d_out;

    const int N = 50000, DIM = 256, QKV = 768;

    float* qkv_buf = (float*)d_ws;                       // N*768 floats
    float* x_buf   = qkv_buf + (size_t)N * QKV;          // N*256 floats

    // 1) qkv = feats @ qkv_w.T + qkv_b
    {
        dim3 grid(QKV / TS, N / TS), block(TS, TS);
        gemm_nt<<<grid, block, 0, stream>>>(feats, qkv_w, qkv_b, qkv_buf, N, QKV, DIM);
    }
    // 2) neighborhood attention -> x
    attn_kernel<<<N, 256, 0, stream>>>(qkv_buf, index_1, x_buf);
    // 3) out = x @ proj_w.T + proj_b
    {
        dim3 grid(DIM / TS, N / TS), block(TS, TS);
        gemm_nt<<<grid, block, 0, stream>>>(x_buf, proj_w, proj_b, out, N, DIM, DIM);
    }
}

// Round 2
// 314.477 us; speedup vs baseline: 6.2201x; 6.2201x over previous
//
#include <hip/hip_runtime.h>
#include <hip/hip_bf16.h>
#include <stdint.h>

typedef __bf16 bf16x8_t __attribute__((ext_vector_type(8)));
typedef float f32x4_t __attribute__((ext_vector_type(4)));

__device__ __forceinline__ float b2f(unsigned short u) {
    union { uint32_t i; float f; } x; x.i = ((uint32_t)u) << 16; return x.f;
}
__device__ __forceinline__ unsigned short f2b(float f) {
    union { float f; uint32_t i; } x; x.f = f;
    uint32_t r = (x.i + 0x7fffu + ((x.i >> 16) & 1u)) >> 16;
    return (unsigned short)r;
}

__global__ void cvt_f32_bf16(const float* __restrict__ in, unsigned short* __restrict__ out, int n) {
    int i = (blockIdx.x * blockDim.x + threadIdx.x) * 4;
    if (i >= n) return;
    const float4 v = *reinterpret_cast<const float4*>(in + i);
    ushort4 o;
    o.x = f2b(v.x); o.y = f2b(v.y); o.z = f2b(v.z); o.w = f2b(v.w);
    *reinterpret_cast<ushort4*>(out + i) = o;
}

// C[m,n] = sum_k A[m,k]*W[n,k] + bias[n]; A: MxK bf16 row-major, W: NxK bf16 row-major.
// 128x128 tile, BK=64, 256 threads (4 waves, 2x2), mfma_f32_16x16x32_bf16.
// Requires Nn % 128 == 0, Kk % 64 == 0. M ragged (row-clamped loads, masked stores).
template <bool OUT_BF16>
__launch_bounds__(256, 2)
__global__ void gemm_bf16(const unsigned short* __restrict__ A,
                          const unsigned short* __restrict__ W,
                          const float* __restrict__ bias,
                          void* __restrict__ Cout,
                          int M, int Nn, int Kk) {
    __shared__ unsigned short As[128 * 64];
    __shared__ unsigned short Bs[128 * 64];
    const int t = threadIdx.x;
    const int w = t >> 6;
    const int l = t & 63;
    const int blockRow = blockIdx.y * 128;
    const int blockCol = blockIdx.x * 128;
    const int wm = w >> 1, wn = w & 1;

    f32x4_t acc[4][4];
#pragma unroll
    for (int i = 0; i < 4; ++i)
#pragma unroll
        for (int j = 0; j < 4; ++j) acc[i][j] = (f32x4_t)0.f;

    const int srow = t >> 3;        // 0..31: row within 32-row chunk
    const int scol = (t & 7) * 8;   // 0,8,...,56: k-offset (elements)

    for (int k0 = 0; k0 < Kk; k0 += 64) {
#pragma unroll
        for (int c = 0; c < 4; ++c) {
            int arow = blockRow + c * 32 + srow;
            arow = arow < M ? arow : M - 1;
            const unsigned short* ga = A + (size_t)arow * Kk + k0 + scol;
            const int brow = blockCol + c * 32 + srow;
            const unsigned short* gb = W + (size_t)brow * Kk + k0 + scol;
            // wave-uniform LDS base; HW adds lane*16 bytes
            unsigned short* la = &As[c * 2048 + w * 512];
            unsigned short* lb = &Bs[c * 2048 + w * 512];
            __builtin_amdgcn_global_load_lds((const __attribute__((address_space(1))) void*)ga,
                                             (__attribute__((address_space(3))) void*)la, 16, 0, 0);
            __builtin_amdgcn_global_load_lds((const __attribute__((address_space(1))) void*)gb,
                                             (__attribute__((address_space(3))) void*)lb, 16, 0, 0);
        }
        __syncthreads();
#pragma unroll
        for (int kc = 0; kc < 2; ++kc) {
            bf16x8_t af[4], bfr[4];
            const int kof = kc * 32 + (l >> 4) * 8;
#pragma unroll
            for (int i = 0; i < 4; ++i) {
                af[i]  = *reinterpret_cast<const bf16x8_t*>(&As[(wm * 64 + i * 16 + (l & 15)) * 64 + kof]);
                bfr[i] = *reinterpret_cast<const bf16x8_t*>(&Bs[(wn * 64 + i * 16 + (l & 15)) * 64 + kof]);
            }
#pragma unroll
            for (int i = 0; i < 4; ++i)
#pragma unroll
                for (int j = 0; j < 4; ++j)
                    acc[i][j] = __builtin_amdgcn_mfma_f32_16x16x32_bf16(af[i], bfr[j], acc[i][j], 0, 0, 0);
        }
        __syncthreads();
    }

    // epilogue: C/D layout col=lane&15, row=(lane>>4)*4+reg
    const int lr = (l >> 4) * 4;
    const int lc = l & 15;
#pragma unroll
    for (int i = 0; i < 4; ++i) {
#pragma unroll
        for (int j = 0; j < 4; ++j) {
            const int col = blockCol + wn * 64 + j * 16 + lc;
            const float bz = bias[col];
#pragma unroll
            for (int r = 0; r < 4; ++r) {
                const int row = blockRow + wm * 64 + i * 16 + lr + r;
                if (row < M) {
                    const float val = acc[i][j][r] + bz;
                    if (OUT_BF16)
                        ((unsigned short*)Cout)[(size_t)row * Nn + col] = f2b(val);
                    else
                        ((float*)Cout)[(size_t)row * Nn + col] = val;
                }
            }
        }
    }
}

// One wave per query. lane = h*8 + p; each lane owns 4 dims (d0 = p*4) of head h.
// qkv: (N,768) bf16 [q|k|v]; x: (N,256) bf16.
__global__ void attn_bf16(const unsigned short* __restrict__ qkv,
                          const int* __restrict__ index_1,
                          unsigned short* __restrict__ x) {
    const int w = threadIdx.x >> 6;
    const int i = blockIdx.x * 4 + w;
    const int l = threadIdx.x & 63;
    const int h = l >> 3;
    const int d0 = (l & 7) * 4;
    const float scale = 0.17677669529663687f;  // 1/sqrt(32)

    const ushort4 qu = *reinterpret_cast<const ushort4*>(&qkv[(size_t)i * 768 + h * 32 + d0]);
    float qx = b2f(qu.x) * scale, qy = b2f(qu.y) * scale,
          qz = b2f(qu.z) * scale, qw = b2f(qu.w) * scale;

    int nbr[16];
#pragma unroll
    for (int m = 0; m < 16; ++m) nbr[m] = index_1[i * 16 + m];

    float s[16];
#pragma unroll
    for (int m = 0; m < 16; ++m) {
        const ushort4 ku = *reinterpret_cast<const ushort4*>(&qkv[(size_t)nbr[m] * 768 + 256 + h * 32 + d0]);
        float p = qx * b2f(ku.x) + qy * b2f(ku.y) + qz * b2f(ku.z) + qw * b2f(ku.w);
        p += __shfl_xor(p, 1, 8);
        p += __shfl_xor(p, 2, 8);
        p += __shfl_xor(p, 4, 8);
        s[m] = p;
    }
    float mx = -1e30f;
#pragma unroll
    for (int m = 0; m < 16; ++m) mx = fmaxf(mx, s[m]);
    float sum = 0.f;
#pragma unroll
    for (int m = 0; m < 16; ++m) { s[m] = __expf(s[m] - mx); sum += s[m]; }
    const float inv = 1.f / sum;

    float ax = 0.f, ay = 0.f, az = 0.f, aw = 0.f;
#pragma unroll
    for (int m = 0; m < 16; ++m) {
        const ushort4 vu = *reinterpret_cast<const ushort4*>(&qkv[(size_t)nbr[m] * 768 + 512 + h * 32 + d0]);
        const float wt = s[m] * inv;
        ax += wt * b2f(vu.x); ay += wt * b2f(vu.y);
        az += wt * b2f(vu.z); aw += wt * b2f(vu.w);
    }
    ushort4 o;
    o.x = f2b(ax); o.y = f2b(ay); o.z = f2b(az); o.w = f2b(aw);
    *reinterpret_cast<ushort4*>(&x[(size_t)i * 256 + h * 32 + d0]) = o;
}

extern "C" void kernel_launch(void* const* d_in, const int* in_sizes, int n_in,
                              void* d_out, int out_size, void* d_ws, size_t ws_size,
                              hipStream_t stream) {
    const float* feats   = (const float*)d_in[0];
    const int*   index_1 = (const int*)d_in[3];
    const float* qkv_w   = (const float*)d_in[6];
    const float* qkv_b   = (const float*)d_in[7];
    const float* proj_w  = (const float*)d_in[8];
    const float* proj_b  = (const float*)d_in[9];
    float* out = (float*)d_out;

    const int N = 50000, DIM = 256, QKVD = 768;

    unsigned short* featsb = (unsigned short*)d_ws;              // N*256
    unsigned short* qkvwb  = featsb + (size_t)N * DIM;           // 768*256
    unsigned short* projwb = qkvwb + (size_t)QKVD * DIM;         // 256*256
    unsigned short* qkvb   = projwb + (size_t)DIM * DIM;         // N*768
    unsigned short* xb     = qkvb + (size_t)N * QKVD;            // N*256

    // fp32 -> bf16 conversions
    cvt_f32_bf16<<<(N * DIM / 4 + 255) / 256, 256, 0, stream>>>(feats, featsb, N * DIM);
    cvt_f32_bf16<<<(QKVD * DIM / 4 + 255) / 256, 256, 0, stream>>>(qkv_w, qkvwb, QKVD * DIM);
    cvt_f32_bf16<<<(DIM * DIM / 4 + 255) / 256, 256, 0, stream>>>(proj_w, projwb, DIM * DIM);

    // 1) qkv = feats @ qkv_w.T + qkv_b   (bf16 out)
    {
        dim3 grid(QKVD / 128, (N + 127) / 128), block(256);
        gemm_bf16<true><<<grid, block, 0, stream>>>(featsb, qkvwb, qkv_b, qkvb, N, QKVD, DIM);
    }
    // 2) neighborhood attention
    attn_bf16<<<N / 4, 256, 0, stream>>>(qkvb, index_1, xb);
    // 3) out = x @ proj_w.T + proj_b   (fp32 out)
    {
        dim3 grid(DIM / 128, (N + 127) / 128), block(256);
        gemm_bf16<false><<<grid, block, 0, stream>>>(xb, projwb, proj_b, out, N, DIM, DIM);
    }
}

// Round 3
// 309.723 us; speedup vs baseline: 6.3156x; 1.0153x over previous
//
#include <hip/hip_runtime.h>
#include <hip/hip_bf16.h>
#include <stdint.h>

typedef __bf16 bf16x8_t __attribute__((ext_vector_type(8)));
typedef float f32x4_t __attribute__((ext_vector_type(4)));

__device__ __forceinline__ float b2f(unsigned short u) {
    union { uint32_t i; float f; } x; x.i = ((uint32_t)u) << 16; return x.f;
}
__device__ __forceinline__ unsigned short f2b(float f) {
    union { float f; uint32_t i; } x; x.f = f;
    uint32_t r = (x.i + 0x7fffu + ((x.i >> 16) & 1u)) >> 16;
    return (unsigned short)r;
}

__global__ void cvt_f32_bf16(const float* __restrict__ in, unsigned short* __restrict__ out, int n) {
    int i = (blockIdx.x * blockDim.x + threadIdx.x) * 4;
    if (i >= n) return;
    const float4 v = *reinterpret_cast<const float4*>(in + i);
    ushort4 o;
    o.x = f2b(v.x); o.y = f2b(v.y); o.z = f2b(v.z); o.w = f2b(v.w);
    *reinterpret_cast<ushort4*>(out + i) = o;
}

// C[m,n] = sum_k A[m,k]*W[n,k] + bias[n]; A: MxK bf16 row-major, W: NxK bf16 row-major.
// 128x128 tile, BK=64, 256 threads (4 waves, 2x2), mfma_f32_16x16x32_bf16.
// 1D grid with XCD swizzle: row-tile r pinned to XCD r%8; col tiles of a row-tile
// are consecutive on the same XCD so the A row-tile is L2-resident across them.
// Launch: gridDim.x = ceil(nRow/8)*8 * nCol  (dummy blocks exit early).
template <bool OUT_BF16>
__launch_bounds__(256, 2)
__global__ void gemm_bf16(const unsigned short* __restrict__ A,
                          const unsigned short* __restrict__ W,
                          const float* __restrict__ bias,
                          void* __restrict__ Cout,
                          int M, int Nn, int Kk) {
    const int nCol = Nn >> 7;
    const int p = blockIdx.x;
    const int xcd = p & 7;
    const int q = p >> 3;
    const int c = q % nCol;
    const int rr = q / nCol;
    const int r = rr * 8 + xcd;
    const int blockRow = r * 128;
    if (blockRow >= M) return;
    const int blockCol = c * 128;

    __shared__ unsigned short As[128 * 64];
    __shared__ unsigned short Bs[128 * 64];
    const int t = threadIdx.x;
    const int w = t >> 6;
    const int l = t & 63;
    const int wm = w >> 1, wn = w & 1;

    f32x4_t acc[4][4];
#pragma unroll
    for (int i = 0; i < 4; ++i)
#pragma unroll
        for (int j = 0; j < 4; ++j) acc[i][j] = (f32x4_t)0.f;

    const int srow = t >> 3;        // 0..31: row within 32-row chunk
    const int scol = (t & 7) * 8;   // 0,8,...,56: k-offset (elements)

    for (int k0 = 0; k0 < Kk; k0 += 64) {
#pragma unroll
        for (int cc = 0; cc < 4; ++cc) {
            int arow = blockRow + cc * 32 + srow;
            arow = arow < M ? arow : M - 1;
            const unsigned short* ga = A + (size_t)arow * Kk + k0 + scol;
            const int brow = blockCol + cc * 32 + srow;
            const unsigned short* gb = W + (size_t)brow * Kk + k0 + scol;
            unsigned short* la = &As[cc * 2048 + w * 512];
            unsigned short* lb = &Bs[cc * 2048 + w * 512];
            __builtin_amdgcn_global_load_lds((const __attribute__((address_space(1))) void*)ga,
                                             (__attribute__((address_space(3))) void*)la, 16, 0, 0);
            __builtin_amdgcn_global_load_lds((const __attribute__((address_space(1))) void*)gb,
                                             (__attribute__((address_space(3))) void*)lb, 16, 0, 0);
        }
        __syncthreads();
#pragma unroll
        for (int kc = 0; kc < 2; ++kc) {
            bf16x8_t af[4], bfr[4];
            const int kof = kc * 32 + (l >> 4) * 8;
#pragma unroll
            for (int i = 0; i < 4; ++i) {
                af[i]  = *reinterpret_cast<const bf16x8_t*>(&As[(wm * 64 + i * 16 + (l & 15)) * 64 + kof]);
                bfr[i] = *reinterpret_cast<const bf16x8_t*>(&Bs[(wn * 64 + i * 16 + (l & 15)) * 64 + kof]);
            }
#pragma unroll
            for (int i = 0; i < 4; ++i)
#pragma unroll
                for (int j = 0; j < 4; ++j)
                    acc[i][j] = __builtin_amdgcn_mfma_f32_16x16x32_bf16(af[i], bfr[j], acc[i][j], 0, 0, 0);
        }
        __syncthreads();
    }

    const int lr = (l >> 4) * 4;
    const int lc = l & 15;
#pragma unroll
    for (int i = 0; i < 4; ++i) {
#pragma unroll
        for (int j = 0; j < 4; ++j) {
            const int col = blockCol + wn * 64 + j * 16 + lc;
            const float bz = bias[col];
#pragma unroll
            for (int rg = 0; rg < 4; ++rg) {
                const int row = blockRow + wm * 64 + i * 16 + lr + rg;
                if (row < M) {
                    const float val = acc[i][j][rg] + bz;
                    if (OUT_BF16)
                        ((unsigned short*)Cout)[(size_t)row * Nn + col] = f2b(val);
                    else
                        ((float*)Cout)[(size_t)row * Nn + col] = val;
                }
            }
        }
    }
}

// One wave per query. lane = h*8 + p; each lane owns 4 dims (d0 = p*4) of head h.
// qkv: (N,768) bf16 [q|k|v]; x: (N,256) bf16.
// All 16 k-rows and v-rows preloaded in paired order (contiguous 1KiB span per
// neighbor) to maximize outstanding misses and DRAM row locality.
__global__ void attn_bf16(const unsigned short* __restrict__ qkv,
                          const int* __restrict__ index_1,
                          unsigned short* __restrict__ x) {
    const int w = threadIdx.x >> 6;
    const int i = blockIdx.x * 4 + w;
    const int l = threadIdx.x & 63;
    const int h = l >> 3;
    const int d0 = (l & 7) * 4;
    const float scale = 0.17677669529663687f;  // 1/sqrt(32)

    int nbr[16];
#pragma unroll
    for (int m = 0; m < 16; ++m) nbr[m] = index_1[i * 16 + m];

    ushort4 kreg[16], vreg[16];
#pragma unroll
    for (int m = 0; m < 16; ++m) {
        const unsigned short* base = qkv + (size_t)nbr[m] * 768 + 256 + h * 32 + d0;
        kreg[m] = *reinterpret_cast<const ushort4*>(base);
        vreg[m] = *reinterpret_cast<const ushort4*>(base + 256);
    }

    const ushort4 qu = *reinterpret_cast<const ushort4*>(&qkv[(size_t)i * 768 + h * 32 + d0]);
    const float qx = b2f(qu.x) * scale, qy = b2f(qu.y) * scale,
                qz = b2f(qu.z) * scale, qw = b2f(qu.w) * scale;

    float s[16];
#pragma unroll
    for (int m = 0; m < 16; ++m) {
        float p = qx * b2f(kreg[m].x) + qy * b2f(kreg[m].y)
                + qz * b2f(kreg[m].z) + qw * b2f(kreg[m].w);
        p += __shfl_xor(p, 1, 8);
        p += __shfl_xor(p, 2, 8);
        p += __shfl_xor(p, 4, 8);
        s[m] = p;
    }
    float mx = -1e30f;
#pragma unroll
    for (int m = 0; m < 16; ++m) mx = fmaxf(mx, s[m]);
    float sum = 0.f;
#pragma unroll
    for (int m = 0; m < 16; ++m) { s[m] = __expf(s[m] - mx); sum += s[m]; }
    const float inv = 1.f / sum;

    float ax = 0.f, ay = 0.f, az = 0.f, aw = 0.f;
#pragma unroll
    for (int m = 0; m < 16; ++m) {
        const float wt = s[m] * inv;
        ax += wt * b2f(vreg[m].x); ay += wt * b2f(vreg[m].y);
        az += wt * b2f(vreg[m].z); aw += wt * b2f(vreg[m].w);
    }
    ushort4 o;
    o.x = f2b(ax); o.y = f2b(ay); o.z = f2b(az); o.w = f2b(aw);
    *reinterpret_cast<ushort4*>(&x[(size_t)i * 256 + h * 32 + d0]) = o;
}

extern "C" void kernel_launch(void* const* d_in, const int* in_sizes, int n_in,
                              void* d_out, int out_size, void* d_ws, size_t ws_size,
                              hipStream_t stream) {
    const float* feats   = (const float*)d_in[0];
    const int*   index_1 = (const int*)d_in[3];
    const float* qkv_w   = (const float*)d_in[6];
    const float* qkv_b   = (const float*)d_in[7];
    const float* proj_w  = (const float*)d_in[8];
    const float* proj_b  = (const float*)d_in[9];
    float* out = (float*)d_out;

    const int N = 50000, DIM = 256, QKVD = 768;

    unsigned short* featsb = (unsigned short*)d_ws;              // N*256
    unsigned short* qkvwb  = featsb + (size_t)N * DIM;           // 768*256
    unsigned short* projwb = qkvwb + (size_t)QKVD * DIM;         // 256*256
    unsigned short* qkvb   = projwb + (size_t)DIM * DIM;         // N*768
    unsigned short* xb     = qkvb + (size_t)N * QKVD;            // N*256

    cvt_f32_bf16<<<(N * DIM / 4 + 255) / 256, 256, 0, stream>>>(feats, featsb, N * DIM);
    cvt_f32_bf16<<<(QKVD * DIM / 4 + 255) / 256, 256, 0, stream>>>(qkv_w, qkvwb, QKVD * DIM);
    cvt_f32_bf16<<<(DIM * DIM / 4 + 255) / 256, 256, 0, stream>>>(proj_w, projwb, DIM * DIM);

    const int nRow = (N + 127) / 128;           // 391
    const int nRowPad = ((nRow + 7) / 8) * 8;   // 392

    // 1) qkv = feats @ qkv_w.T + qkv_b   (bf16 out)
    gemm_bf16<true><<<nRowPad * (QKVD / 128), 256, 0, stream>>>(featsb, qkvwb, qkv_b, qkvb, N, QKVD, DIM);
    // 2) neighborhood attention
    attn_bf16<<<N / 4, 256, 0, stream>>>(qkvb, index_1, xb);
    // 3) out = x @ proj_w.T + proj_b   (fp32 out)
    gemm_bf16<false><<<nRowPad * (DIM / 128), 256, 0, stream>>>(xb, projwb, proj_b, out, N, DIM, DIM);
}

// Round 4
// 307.423 us; speedup vs baseline: 6.3629x; 1.0075x over previous
//
#include <hip/hip_runtime.h>
#include <hip/hip_bf16.h>
#include <stdint.h>

typedef __bf16 bf16x8_t __attribute__((ext_vector_type(8)));
typedef float f32x4_t __attribute__((ext_vector_type(4)));

__device__ __forceinline__ float b2f(unsigned short u) {
    union { uint32_t i; float f; } x; x.i = ((uint32_t)u) << 16; return x.f;
}
__device__ __forceinline__ unsigned short f2b(float f) {
    union { float f; uint32_t i; } x; x.f = f;
    uint32_t r = (x.i + 0x7fffu + ((x.i >> 16) & 1u)) >> 16;
    return (unsigned short)r;
}

#define QSCALE 0.17677669529663687f  /* 1/sqrt(32) */

__global__ void cvt_f32_bf16(const float* __restrict__ in, unsigned short* __restrict__ out, int n) {
    int i = (blockIdx.x * blockDim.x + threadIdx.x) * 4;
    if (i >= n) return;
    const float4 v = *reinterpret_cast<const float4*>(in + i);
    ushort4 o;
    o.x = f2b(v.x); o.y = f2b(v.y); o.z = f2b(v.z); o.w = f2b(v.w);
    *reinterpret_cast<ushort4*>(out + i) = o;
}

// One-shot prep: convert qkv_w (q-rows pre-scaled), proj_w, and make scaled fp32 qkv_b copy.
__global__ void prep_weights(const float* __restrict__ qkv_w, const float* __restrict__ proj_w,
                             const float* __restrict__ qkv_b,
                             unsigned short* __restrict__ qkvwb, unsigned short* __restrict__ projwb,
                             float* __restrict__ qkvbS) {
    const int idx = blockIdx.x * 256 + threadIdx.x;   // one float4-group per thread
    if (idx < 49152) {                                 // qkv_w: 768*256 / 4
        const int e = idx * 4;
        const float4 v = *reinterpret_cast<const float4*>(qkv_w + e);
        const float sc = (e >> 8) < 256 ? QSCALE : 1.f;  // rows [0,256) are q
        ushort4 o;
        o.x = f2b(v.x * sc); o.y = f2b(v.y * sc); o.z = f2b(v.z * sc); o.w = f2b(v.w * sc);
        *reinterpret_cast<ushort4*>(qkvwb + e) = o;
    } else if (idx < 49152 + 16384) {                  // proj_w: 256*256 / 4
        const int e = (idx - 49152) * 4;
        const float4 v = *reinterpret_cast<const float4*>(proj_w + e);
        ushort4 o;
        o.x = f2b(v.x); o.y = f2b(v.y); o.z = f2b(v.z); o.w = f2b(v.w);
        *reinterpret_cast<ushort4*>(projwb + e) = o;
    } else if (idx < 49152 + 16384 + 192) {            // qkv_b: 768 / 4
        const int e = (idx - 49152 - 16384) * 4;
        float4 v = *reinterpret_cast<const float4*>(qkv_b + e);
        if (e < 256) { v.x *= QSCALE; v.y *= QSCALE; v.z *= QSCALE; v.w *= QSCALE; }
        *reinterpret_cast<float4*>(qkvbS + e) = v;
    }
}

// C[m,n] = sum_k A[m,k]*W[n,k] + bias[n]; A: MxK bf16 row-major, W: NxK bf16 row-major.
// 128x128 tile, BK=64, 256 threads (4 waves 2x2), mfma_f32_16x16x32_bf16.
// XCD-swizzled 1D grid. OUT_MODE: 0 = fp32 C (MxNn), 1 = bf16 split into
// 256-col sections each stored as (M,256) at out + (col>>8)*M*256.
template <int OUT_MODE>
__launch_bounds__(256, 2)
__global__ void gemm_bf16(const unsigned short* __restrict__ A,
                          const unsigned short* __restrict__ W,
                          const float* __restrict__ bias,
                          void* __restrict__ Cout,
                          int M, int Nn, int Kk) {
    const int nCol = Nn >> 7;
    const int p = blockIdx.x;
    const int xcd = p & 7;
    const int q = p >> 3;
    const int c = q % nCol;
    const int rr = q / nCol;
    const int r = rr * 8 + xcd;
    const int blockRow = r * 128;
    if (blockRow >= M) return;
    const int blockCol = c * 128;

    __shared__ unsigned short As[128 * 64];
    __shared__ unsigned short Bs[128 * 64];
    const int t = threadIdx.x;
    const int w = t >> 6;
    const int l = t & 63;
    const int wm = w >> 1, wn = w & 1;

    f32x4_t acc[4][4];
#pragma unroll
    for (int i = 0; i < 4; ++i)
#pragma unroll
        for (int j = 0; j < 4; ++j) acc[i][j] = (f32x4_t)0.f;

    const int srow = t >> 3;
    const int scol = (t & 7) * 8;

    for (int k0 = 0; k0 < Kk; k0 += 64) {
#pragma unroll
        for (int cc = 0; cc < 4; ++cc) {
            int arow = blockRow + cc * 32 + srow;
            arow = arow < M ? arow : M - 1;
            const unsigned short* ga = A + (size_t)arow * Kk + k0 + scol;
            const int brow = blockCol + cc * 32 + srow;
            const unsigned short* gb = W + (size_t)brow * Kk + k0 + scol;
            unsigned short* la = &As[cc * 2048 + w * 512];
            unsigned short* lb = &Bs[cc * 2048 + w * 512];
            __builtin_amdgcn_global_load_lds((const __attribute__((address_space(1))) void*)ga,
                                             (__attribute__((address_space(3))) void*)la, 16, 0, 0);
            __builtin_amdgcn_global_load_lds((const __attribute__((address_space(1))) void*)gb,
                                             (__attribute__((address_space(3))) void*)lb, 16, 0, 0);
        }
        __syncthreads();
#pragma unroll
        for (int kc = 0; kc < 2; ++kc) {
            bf16x8_t af[4], bfr[4];
            const int kof = kc * 32 + (l >> 4) * 8;
#pragma unroll
            for (int i = 0; i < 4; ++i) {
                af[i]  = *reinterpret_cast<const bf16x8_t*>(&As[(wm * 64 + i * 16 + (l & 15)) * 64 + kof]);
                bfr[i] = *reinterpret_cast<const bf16x8_t*>(&Bs[(wn * 64 + i * 16 + (l & 15)) * 64 + kof]);
            }
#pragma unroll
            for (int i = 0; i < 4; ++i)
#pragma unroll
                for (int j = 0; j < 4; ++j)
                    acc[i][j] = __builtin_amdgcn_mfma_f32_16x16x32_bf16(af[i], bfr[j], acc[i][j], 0, 0, 0);
        }
        __syncthreads();
    }

    const int lr = (l >> 4) * 4;
    const int lc = l & 15;
#pragma unroll
    for (int i = 0; i < 4; ++i) {
#pragma unroll
        for (int j = 0; j < 4; ++j) {
            const int col = blockCol + wn * 64 + j * 16 + lc;
            const float bz = bias[col];
#pragma unroll
            for (int rg = 0; rg < 4; ++rg) {
                const int row = blockRow + wm * 64 + i * 16 + lr + rg;
                if (row < M) {
                    const float val = acc[i][j][rg] + bz;
                    if (OUT_MODE == 0) {
                        ((float*)Cout)[(size_t)row * Nn + col] = val;
                    } else {
                        const size_t sec = (size_t)(col >> 8) * (size_t)M * 256;
                        ((unsigned short*)Cout)[sec + (size_t)row * 256 + (col & 255)] = f2b(val);
                    }
                }
            }
        }
    }
}

// Pass 1: logits + softmax -> normalized weights (bf16).
// One wave per query; lane = h*8+p owns dims d0=p*4.. of head h.
// qb pre-scaled by 1/sqrt(32). wbuf: (N,128) bf16, [h][m] layout.
__global__ void attn_logits(const unsigned short* __restrict__ qb,
                            const unsigned short* __restrict__ kb,
                            const int* __restrict__ index_1,
                            unsigned short* __restrict__ wbuf) {
    const int w = threadIdx.x >> 6;
    const int i = blockIdx.x * 4 + w;
    const int l = threadIdx.x & 63;
    const int h = l >> 3;
    const int p = l & 7;
    const int d0 = p * 4;

    int nbr[16];
#pragma unroll
    for (int m = 0; m < 16; ++m) nbr[m] = index_1[i * 16 + m];

    ushort4 kreg[16];
#pragma unroll
    for (int m = 0; m < 16; ++m)
        kreg[m] = *reinterpret_cast<const ushort4*>(&kb[(size_t)nbr[m] * 256 + h * 32 + d0]);

    const ushort4 qu = *reinterpret_cast<const ushort4*>(&qb[(size_t)i * 256 + h * 32 + d0]);
    const float qx = b2f(qu.x), qy = b2f(qu.y), qz = b2f(qu.z), qw = b2f(qu.w);

    float s[16];
#pragma unroll
    for (int m = 0; m < 16; ++m) {
        float pv = qx * b2f(kreg[m].x) + qy * b2f(kreg[m].y)
                 + qz * b2f(kreg[m].z) + qw * b2f(kreg[m].w);
        pv += __shfl_xor(pv, 1, 8);
        pv += __shfl_xor(pv, 2, 8);
        pv += __shfl_xor(pv, 4, 8);
        s[m] = pv;
    }
    float mx = -1e30f;
#pragma unroll
    for (int m = 0; m < 16; ++m) mx = fmaxf(mx, s[m]);
    float sum = 0.f;
#pragma unroll
    for (int m = 0; m < 16; ++m) { s[m] = __expf(s[m] - mx); sum += s[m]; }
    const float inv = 1.f / sum;

    // lane p writes its pair (m=2p, 2p+1) packed as 2x bf16
    const uint32_t pack = (uint32_t)f2b(s[2 * p] * inv) | ((uint32_t)f2b(s[2 * p + 1] * inv) << 16);
    ((uint32_t*)wbuf)[(size_t)i * 64 + h * 8 + p] = pack;
}

// Pass 2: x[i] = sum_m w[h][m] * v[nbr[m]]
__global__ void attn_out(const unsigned short* __restrict__ vb,
                         const unsigned short* __restrict__ wbuf,
                         const int* __restrict__ index_1,
                         unsigned short* __restrict__ xb) {
    const int w = threadIdx.x >> 6;
    const int i = blockIdx.x * 4 + w;
    const int l = threadIdx.x & 63;
    const int h = l >> 3;
    const int p = l & 7;
    const int d0 = p * 4;

    int nbr[16];
#pragma unroll
    for (int m = 0; m < 16; ++m) nbr[m] = index_1[i * 16 + m];

    ushort4 vreg[16];
#pragma unroll
    for (int m = 0; m < 16; ++m)
        vreg[m] = *reinterpret_cast<const ushort4*>(&vb[(size_t)nbr[m] * 256 + h * 32 + d0]);

    const uint32_t wp = ((const uint32_t*)wbuf)[(size_t)i * 64 + h * 8 + p];

    float ax = 0.f, ay = 0.f, az = 0.f, aw = 0.f;
#pragma unroll
    for (int m = 0; m < 16; ++m) {
        const uint32_t src = __shfl(wp, h * 8 + (m >> 1), 64);
        const float wt = b2f((unsigned short)((m & 1) ? (src >> 16) : (src & 0xffff)));
        ax += wt * b2f(vreg[m].x); ay += wt * b2f(vreg[m].y);
        az += wt * b2f(vreg[m].z); aw += wt * b2f(vreg[m].w);
    }
    ushort4 o;
    o.x = f2b(ax); o.y = f2b(ay); o.z = f2b(az); o.w = f2b(aw);
    *reinterpret_cast<ushort4*>(&xb[(size_t)i * 256 + h * 32 + d0]) = o;
}

extern "C" void kernel_launch(void* const* d_in, const int* in_sizes, int n_in,
                              void* d_out, int out_size, void* d_ws, size_t ws_size,
                              hipStream_t stream) {
    const float* feats   = (const float*)d_in[0];
    const int*   index_1 = (const int*)d_in[3];
    const float* qkv_w   = (const float*)d_in[6];
    const float* qkv_b   = (const float*)d_in[7];
    const float* proj_w  = (const float*)d_in[8];
    const float* proj_b  = (const float*)d_in[9];
    float* out = (float*)d_out;

    const int N = 50000, DIM = 256, QKVD = 768;

    unsigned short* featsb = (unsigned short*)d_ws;              // N*256
    unsigned short* qkvwb  = featsb + (size_t)N * DIM;           // 768*256
    unsigned short* projwb = qkvwb + (size_t)QKVD * DIM;         // 256*256
    float*          qkvbS  = (float*)(projwb + (size_t)DIM * DIM); // 768 floats
    unsigned short* qb     = (unsigned short*)(qkvbS + QKVD);    // N*256 (q, pre-scaled)
    unsigned short* kb     = qb + (size_t)N * DIM;               // N*256
    unsigned short* vb     = kb + (size_t)N * DIM;               // N*256
    unsigned short* xb     = vb + (size_t)N * DIM;               // N*256
    unsigned short* wbuf   = xb + (size_t)N * DIM;               // N*128

    cvt_f32_bf16<<<(N * DIM / 4 + 255) / 256, 256, 0, stream>>>(feats, featsb, N * DIM);
    prep_weights<<<(49152 + 16384 + 192 + 255) / 256, 256, 0, stream>>>(
        qkv_w, proj_w, qkv_b, qkvwb, projwb, qkvbS);

    const int nRow = (N + 127) / 128;           // 391
    const int nRowPad = ((nRow + 7) / 8) * 8;   // 392

    // 1) qkv = feats @ qkv_w.T + qkv_bS -> split q|k|v bf16 arrays (q pre-scaled)
    gemm_bf16<1><<<nRowPad * (QKVD / 128), 256, 0, stream>>>(featsb, qkvwb, qkvbS, qb, N, QKVD, DIM);
    // 2a) logits + softmax -> weights
    attn_logits<<<N / 4, 256, 0, stream>>>(qb, kb, index_1, wbuf);
    // 2b) weighted V gather -> x
    attn_out<<<N / 4, 256, 0, stream>>>(vb, wbuf, index_1, xb);
    // 3) out = x @ proj_w.T + proj_b (fp32)
    gemm_bf16<0><<<nRowPad * (DIM / 128), 256, 0, stream>>>(xb, projwb, proj_b, out, N, DIM, DIM);
}

// Round 5
// 294.400 us; speedup vs baseline: 6.6443x; 1.0442x over previous
//
#include <hip/hip_runtime.h>
#include <hip/hip_bf16.h>
#include <stdint.h>

typedef __bf16 bf16x8_t __attribute__((ext_vector_type(8)));
typedef float f32x4_t __attribute__((ext_vector_type(4)));

__device__ __forceinline__ float b2f(unsigned short u) {
    union { uint32_t i; float f; } x; x.i = ((uint32_t)u) << 16; return x.f;
}
__device__ __forceinline__ unsigned short f2b(float f) {
    union { float f; uint32_t i; } x; x.f = f;
    uint32_t r = (x.i + 0x7fffu + ((x.i >> 16) & 1u)) >> 16;
    return (unsigned short)r;
}

#define QSCALE 0.17677669529663687f  /* 1/sqrt(32) */

__global__ void cvt_f32_bf16(const float* __restrict__ in, unsigned short* __restrict__ out, int n) {
    int i = (blockIdx.x * blockDim.x + threadIdx.x) * 4;
    if (i >= n) return;
    const float4 v = *reinterpret_cast<const float4*>(in + i);
    ushort4 o;
    o.x = f2b(v.x); o.y = f2b(v.y); o.z = f2b(v.z); o.w = f2b(v.w);
    *reinterpret_cast<ushort4*>(out + i) = o;
}

// One-shot prep: convert qkv_w (q-rows pre-scaled), proj_w, and make scaled fp32 qkv_b copy.
__global__ void prep_weights(const float* __restrict__ qkv_w, const float* __restrict__ proj_w,
                             const float* __restrict__ qkv_b,
                             unsigned short* __restrict__ qkvwb, unsigned short* __restrict__ projwb,
                             float* __restrict__ qkvbS) {
    const int idx = blockIdx.x * 256 + threadIdx.x;
    if (idx < 49152) {                                 // qkv_w: 768*256 / 4
        const int e = idx * 4;
        const float4 v = *reinterpret_cast<const float4*>(qkv_w + e);
        const float sc = (e >> 8) < 256 ? QSCALE : 1.f;  // rows [0,256) are q
        ushort4 o;
        o.x = f2b(v.x * sc); o.y = f2b(v.y * sc); o.z = f2b(v.z * sc); o.w = f2b(v.w * sc);
        *reinterpret_cast<ushort4*>(qkvwb + e) = o;
    } else if (idx < 49152 + 16384) {                  // proj_w: 256*256 / 4
        const int e = (idx - 49152) * 4;
        const float4 v = *reinterpret_cast<const float4*>(proj_w + e);
        ushort4 o;
        o.x = f2b(v.x); o.y = f2b(v.y); o.z = f2b(v.z); o.w = f2b(v.w);
        *reinterpret_cast<ushort4*>(projwb + e) = o;
    } else if (idx < 49152 + 16384 + 192) {            // qkv_b: 768 / 4
        const int e = (idx - 49152 - 16384) * 4;
        float4 v = *reinterpret_cast<const float4*>(qkv_b + e);
        if (e < 256) { v.x *= QSCALE; v.y *= QSCALE; v.z *= QSCALE; v.w *= QSCALE; }
        *reinterpret_cast<float4*>(qkvbS + e) = v;
    }
}

// C[m,n] = sum_k A[m,k]*W[n,k] + bias[n]; A: MxK bf16 row-major, W: NxK bf16 row-major.
// 128x128 tile, BK=64, 256 threads (4 waves 2x2), mfma_f32_16x16x32_bf16.
// LDS XOR swizzle: 16B col-block cb of row r stored at cb ^ (r&7); staging lane
// loads global col-block (l&7)^(l>>3) (its row key is l>>3), readers XOR with
// row&7 (= l&7). Breaks the 16-way row-stride-128B bank conflict -> 2-way (free).
// XCD-swizzled 1D grid. OUT_MODE: 0 = fp32 C (MxNn), 1 = bf16 split into
// 256-col sections each stored as (M,256) at out + (col>>8)*M*256.
template <int OUT_MODE>
__launch_bounds__(256, 2)
__global__ void gemm_bf16(const unsigned short* __restrict__ A,
                          const unsigned short* __restrict__ W,
                          const float* __restrict__ bias,
                          void* __restrict__ Cout,
                          int M, int Nn, int Kk) {
    const int nCol = Nn >> 7;
    const int p = blockIdx.x;
    const int xcd = p & 7;
    const int q = p >> 3;
    const int c = q % nCol;
    const int rr = q / nCol;
    const int r = rr * 8 + xcd;
    const int blockRow = r * 128;
    if (blockRow >= M) return;
    const int blockCol = c * 128;

    __shared__ unsigned short As[128 * 64];
    __shared__ unsigned short Bs[128 * 64];
    const int t = threadIdx.x;
    const int w = t >> 6;
    const int l = t & 63;
    const int wm = w >> 1, wn = w & 1;

    f32x4_t acc[4][4];
#pragma unroll
    for (int i = 0; i < 4; ++i)
#pragma unroll
        for (int j = 0; j < 4; ++j) acc[i][j] = (f32x4_t)0.f;

    const int srow = t >> 3;                         // 0..31: row within 32-row chunk
    const int scol = (((t & 7) ^ ((t >> 3) & 7)) * 8);  // swizzled global col-block

    for (int k0 = 0; k0 < Kk; k0 += 64) {
#pragma unroll
        for (int cc = 0; cc < 4; ++cc) {
            int arow = blockRow + cc * 32 + srow;
            arow = arow < M ? arow : M - 1;
            const unsigned short* ga = A + (size_t)arow * Kk + k0 + scol;
            const int brow = blockCol + cc * 32 + srow;
            const unsigned short* gb = W + (size_t)brow * Kk + k0 + scol;
            unsigned short* la = &As[cc * 2048 + w * 512];
            unsigned short* lb = &Bs[cc * 2048 + w * 512];
            __builtin_amdgcn_global_load_lds((const __attribute__((address_space(1))) void*)ga,
                                             (__attribute__((address_space(3))) void*)la, 16, 0, 0);
            __builtin_amdgcn_global_load_lds((const __attribute__((address_space(1))) void*)gb,
                                             (__attribute__((address_space(3))) void*)lb, 16, 0, 0);
        }
        __syncthreads();
        const int l15 = l & 15;
        const int lk = l >> 4;      // 0..3
        const int key = l & 7;      // row&7 for reader rows
#pragma unroll
        for (int kc = 0; kc < 2; ++kc) {
            bf16x8_t af[4], bfr[4];
            const int cb = kc * 4 + lk;
            const int kof = (cb ^ key) * 8;
#pragma unroll
            for (int i = 0; i < 4; ++i) {
                af[i]  = *reinterpret_cast<const bf16x8_t*>(&As[(wm * 64 + i * 16 + l15) * 64 + kof]);
                bfr[i] = *reinterpret_cast<const bf16x8_t*>(&Bs[(wn * 64 + i * 16 + l15) * 64 + kof]);
            }
#pragma unroll
            for (int i = 0; i < 4; ++i)
#pragma unroll
                for (int j = 0; j < 4; ++j)
                    acc[i][j] = __builtin_amdgcn_mfma_f32_16x16x32_bf16(af[i], bfr[j], acc[i][j], 0, 0, 0);
        }
        __syncthreads();
    }

    const int lr = (l >> 4) * 4;
    const int lc = l & 15;
#pragma unroll
    for (int i = 0; i < 4; ++i) {
#pragma unroll
        for (int j = 0; j < 4; ++j) {
            const int col = blockCol + wn * 64 + j * 16 + lc;
            const float bz = bias[col];
#pragma unroll
            for (int rg = 0; rg < 4; ++rg) {
                const int row = blockRow + wm * 64 + i * 16 + lr + rg;
                if (row < M) {
                    const float val = acc[i][j][rg] + bz;
                    if (OUT_MODE == 0) {
                        ((float*)Cout)[(size_t)row * Nn + col] = val;
                    } else {
                        const size_t sec = (size_t)(col >> 8) * (size_t)M * 256;
                        ((unsigned short*)Cout)[sec + (size_t)row * 256 + (col & 255)] = f2b(val);
                    }
                }
            }
        }
    }
}

// Pass 1: logits + softmax -> normalized weights (bf16).
__global__ void attn_logits(const unsigned short* __restrict__ qb,
                            const unsigned short* __restrict__ kb,
                            const int* __restrict__ index_1,
                            unsigned short* __restrict__ wbuf) {
    const int w = threadIdx.x >> 6;
    const int i = blockIdx.x * 4 + w;
    const int l = threadIdx.x & 63;
    const int h = l >> 3;
    const int p = l & 7;
    const int d0 = p * 4;

    int nbr[16];
#pragma unroll
    for (int m = 0; m < 16; ++m) nbr[m] = index_1[i * 16 + m];

    ushort4 kreg[16];
#pragma unroll
    for (int m = 0; m < 16; ++m)
        kreg[m] = *reinterpret_cast<const ushort4*>(&kb[(size_t)nbr[m] * 256 + h * 32 + d0]);

    const ushort4 qu = *reinterpret_cast<const ushort4*>(&qb[(size_t)i * 256 + h * 32 + d0]);
    const float qx = b2f(qu.x), qy = b2f(qu.y), qz = b2f(qu.z), qw = b2f(qu.w);

    float s[16];
#pragma unroll
    for (int m = 0; m < 16; ++m) {
        float pv = qx * b2f(kreg[m].x) + qy * b2f(kreg[m].y)
                 + qz * b2f(kreg[m].z) + qw * b2f(kreg[m].w);
        pv += __shfl_xor(pv, 1, 8);
        pv += __shfl_xor(pv, 2, 8);
        pv += __shfl_xor(pv, 4, 8);
        s[m] = pv;
    }
    float mx = -1e30f;
#pragma unroll
    for (int m = 0; m < 16; ++m) mx = fmaxf(mx, s[m]);
    float sum = 0.f;
#pragma unroll
    for (int m = 0; m < 16; ++m) { s[m] = __expf(s[m] - mx); sum += s[m]; }
    const float inv = 1.f / sum;

    const uint32_t pack = (uint32_t)f2b(s[2 * p] * inv) | ((uint32_t)f2b(s[2 * p + 1] * inv) << 16);
    ((uint32_t*)wbuf)[(size_t)i * 64 + h * 8 + p] = pack;
}

// Pass 2: x[i] = sum_m w[h][m] * v[nbr[m]]
__global__ void attn_out(const unsigned short* __restrict__ vb,
                         const unsigned short* __restrict__ wbuf,
                         const int* __restrict__ index_1,
                         unsigned short* __restrict__ xb) {
    const int w = threadIdx.x >> 6;
    const int i = blockIdx.x * 4 + w;
    const int l = threadIdx.x & 63;
    const int h = l >> 3;
    const int p = l & 7;
    const int d0 = p * 4;

    int nbr[16];
#pragma unroll
    for (int m = 0; m < 16; ++m) nbr[m] = index_1[i * 16 + m];

    ushort4 vreg[16];
#pragma unroll
    for (int m = 0; m < 16; ++m)
        vreg[m] = *reinterpret_cast<const ushort4*>(&vb[(size_t)nbr[m] * 256 + h * 32 + d0]);

    const uint32_t wp = ((const uint32_t*)wbuf)[(size_t)i * 64 + h * 8 + p];

    float ax = 0.f, ay = 0.f, az = 0.f, aw = 0.f;
#pragma unroll
    for (int m = 0; m < 16; ++m) {
        const uint32_t src = __shfl(wp, h * 8 + (m >> 1), 64);
        const float wt = b2f((unsigned short)((m & 1) ? (src >> 16) : (src & 0xffff)));
        ax += wt * b2f(vreg[m].x); ay += wt * b2f(vreg[m].y);
        az += wt * b2f(vreg[m].z); aw += wt * b2f(vreg[m].w);
    }
    ushort4 o;
    o.x = f2b(ax); o.y = f2b(ay); o.z = f2b(az); o.w = f2b(aw);
    *reinterpret_cast<ushort4*>(&xb[(size_t)i * 256 + h * 32 + d0]) = o;
}

extern "C" void kernel_launch(void* const* d_in, const int* in_sizes, int n_in,
                              void* d_out, int out_size, void* d_ws, size_t ws_size,
                              hipStream_t stream) {
    const float* feats   = (const float*)d_in[0];
    const int*   index_1 = (const int*)d_in[3];
    const float* qkv_w   = (const float*)d_in[6];
    const float* qkv_b   = (const float*)d_in[7];
    const float* proj_w  = (const float*)d_in[8];
    const float* proj_b  = (const float*)d_in[9];
    float* out = (float*)d_out;

    const int N = 50000, DIM = 256, QKVD = 768;

    unsigned short* featsb = (unsigned short*)d_ws;              // N*256
    unsigned short* qkvwb  = featsb + (size_t)N * DIM;           // 768*256
    unsigned short* projwb = qkvwb + (size_t)QKVD * DIM;         // 256*256
    float*          qkvbS  = (float*)(projwb + (size_t)DIM * DIM); // 768 floats
    unsigned short* qb     = (unsigned short*)(qkvbS + QKVD);    // N*256 (q, pre-scaled)
    unsigned short* kb     = qb + (size_t)N * DIM;               // N*256
    unsigned short* vb     = kb + (size_t)N * DIM;               // N*256
    unsigned short* xb     = vb + (size_t)N * DIM;               // N*256
    unsigned short* wbuf   = xb + (size_t)N * DIM;               // N*128

    cvt_f32_bf16<<<(N * DIM / 4 + 255) / 256, 256, 0, stream>>>(feats, featsb, N * DIM);
    prep_weights<<<(49152 + 16384 + 192 + 255) / 256, 256, 0, stream>>>(
        qkv_w, proj_w, qkv_b, qkvwb, projwb, qkvbS);

    const int nRow = (N + 127) / 128;           // 391
    const int nRowPad = ((nRow + 7) / 8) * 8;   // 392

    // 1) qkv = feats @ qkv_w.T + qkv_bS -> split q|k|v bf16 arrays (q pre-scaled)
    gemm_bf16<1><<<nRowPad * (QKVD / 128), 256, 0, stream>>>(featsb, qkvwb, qkvbS, qb, N, QKVD, DIM);
    // 2a) logits + softmax -> weights
    attn_logits<<<N / 4, 256, 0, stream>>>(qb, kb, index_1, wbuf);
    // 2b) weighted V gather -> x
    attn_out<<<N / 4, 256, 0, stream>>>(vb, wbuf, index_1, xb);
    // 3) out = x @ proj_w.T + proj_b (fp32)
    gemm_bf16<0><<<nRowPad * (DIM / 128), 256, 0, stream>>>(xb, projwb, proj_b, out, N, DIM, DIM);
}